// Round 5
// baseline (243.158 us; speedup 1.0000x reference)
//
#include <hip/hip_runtime.h>
#include <hip/hip_bf16.h>
#include <stdint.h>

#define B_ 4
#define S_ 2048
#define H_ 1024
#define NH_ 16
#define HD_ 64
#define SCALE_ 0.125f
#define LOG2E_ 1.4426950408889634f

typedef __bf16 bf16x8 __attribute__((ext_vector_type(8)));
typedef float f32x4 __attribute__((ext_vector_type(4)));
typedef unsigned short us4 __attribute__((ext_vector_type(4)));
typedef unsigned short us8 __attribute__((ext_vector_type(8)));
typedef unsigned short ushort_t;

__device__ __forceinline__ ushort_t f2bf(float f) {
  union { float f; uint32_t u; } a; a.f = f;
  uint32_t r = (a.u + 0x7fffu + ((a.u >> 16) & 1u)) >> 16;
  return (ushort_t)r;
}

__device__ __forceinline__ void async16(const void* g, void* l) {
  __builtin_amdgcn_global_load_lds(
      (const __attribute__((address_space(1))) unsigned int*)(uintptr_t)g,
      (__attribute__((address_space(3))) unsigned int*)(uintptr_t)l, 16, 0, 0);
}

// ---------------- convert hidden_states fp32 -> bf16 ----------------
__global__ __launch_bounds__(256) void conv_x(const float4* __restrict__ x,
                                              ushort_t* __restrict__ xb) {
  int i = blockIdx.x * 256 + threadIdx.x;
  float4 v = x[i];
  us4 o;
  o.x = f2bf(v.x); o.y = f2bf(v.y); o.z = f2bf(v.z); o.w = f2bf(v.w);
  *(us4*)(xb + (size_t)i * 4) = o;
}

// ------- conv+transpose W[k][n] -> Wt[w][n][k], LDS-tiled 64x64 ------
__global__ __launch_bounds__(256) void conv_w(const float* __restrict__ Wq,
                                              const float* __restrict__ Wk,
                                              const float* __restrict__ Wv,
                                              ushort_t* __restrict__ Wt) {
  __shared__ __align__(16) ushort_t T[64 * 64];
  int bid = blockIdx.x;            // 0..767
  int w = bid >> 8;
  int t2 = bid & 255;
  int kt = (t2 >> 4) * 64, nt = (t2 & 15) * 64;
  const float* W = (w == 0) ? Wq : (w == 1) ? Wk : Wv;
  int tid = threadIdx.x;
  int k = tid >> 2, nq = tid & 3;
#pragma unroll
  for (int j4 = 0; j4 < 4; ++j4) {
    int n = nq * 4 + j4 * 16;
    float4 f = *(const float4*)(W + (size_t)(kt + k) * H_ + nt + n);
    us4 o;
    o.x = f2bf(f.x); o.y = f2bf(f.y); o.z = f2bf(f.z); o.w = f2bf(f.w);
    *(us4*)(T + k * 64 + (((n >> 3) ^ (k & 7)) * 8) + (n & 7)) = o;
  }
  __syncthreads();
  int n2 = tid >> 2, kq = tid & 3;
  us8 o0, o1;
#pragma unroll
  for (int j = 0; j < 16; ++j) {
    int kk = kq * 16 + j;
    ushort_t v = T[kk * 64 + (((n2 >> 3) ^ (kk & 7)) * 8) + (n2 & 7)];
    if (j < 8) o0[j] = v; else o1[j - 8] = v;
  }
  size_t obase = (size_t)w * (H_ * H_) + (size_t)(nt + n2) * H_ + kt + kq * 16;
  *(us8*)(Wt + obase) = o0;
  *(us8*)(Wt + obase + 8) = o1;
}

// ---------------- fused QKV GEMM (m97 recipe, BK=64) -----------------
// Round-4 WIN kept as-is: 2-phase single-buffer, BK=64, XOR-8 LDS
// swizzle (conflicts -> 0), pre-swizzled global source.
// w==2 (V) epilogue writes transposed [bh][d][s] into the V slot so attn
// can stage V^T directly.
__global__ __launch_bounds__(256) void qkv_gemm(const ushort_t* __restrict__ Xb,
                                                const ushort_t* __restrict__ Wt,
                                                const float* __restrict__ bq,
                                                const float* __restrict__ bk,
                                                const float* __restrict__ bv,
                                                ushort_t* __restrict__ QKV) {
  __shared__ __align__(16) ushort_t As[128 * 64];   // 16 KB
  __shared__ __align__(16) ushort_t Bs[128 * 64];   // 16 KB
  int nb = blockIdx.x;             // 0..23
  int mb = blockIdx.y;             // 0..63
  int w = nb >> 3;
  int n_base = (nb & 7) * 128;
  int m_base = mb * 128;
  const ushort_t* Wtw = Wt + (size_t)w * (H_ * H_);
  int tid = threadIdx.x;
  int lane = tid & 63, wave = tid >> 6;
  int wr = wave >> 1, wc = wave & 1;
  int g = lane >> 4, l15 = lane & 15;

  f32x4 acc[4][4];
#pragma unroll
  for (int i = 0; i < 4; i++)
#pragma unroll
    for (int j = 0; j < 4; j++) acc[i][j] = (f32x4){0.f, 0.f, 0.f, 0.f};

  // staging: 8 chunks/thread/iter (4 for A, 4 for B). chunk id = tid+it*256
  // -> (row = id>>3, slot = id&7); rows step by 32 per it (low 3 bits of
  // row invariant -> one source-column xor per thread).
  int r0 = tid >> 3, sl = tid & 7;
  int cc = sl ^ (r0 & 7);
  const ushort_t* sA = Xb + (size_t)(m_base + r0) * H_ + cc * 8;
  const ushort_t* sB = Wtw + (size_t)(n_base + r0) * H_ + cc * 8;
  int la = tid * 8;                // ushort offset of chunk id (it adds 2048)

  for (int kt = 0; kt < 16; ++kt) {
    int k0 = kt * 64;
    __syncthreads();
#pragma unroll
    for (int it = 0; it < 4; ++it) {
      async16(sA + (size_t)it * 32 * H_ + k0, As + la + it * 2048);
      async16(sB + (size_t)it * 32 * H_ + k0, Bs + la + it * 2048);
    }
    __builtin_amdgcn_s_waitcnt(0);
    __syncthreads();

#pragma unroll
    for (int ks = 0; ks < 2; ++ks) {
      bf16x8 af[4], bfr[4];
#pragma unroll
      for (int mi = 0; mi < 4; mi++) {
        int row = wr * 64 + mi * 16 + l15;
        af[mi] = *(const bf16x8*)(As + row * 64 + (((ks * 4 + g) ^ (row & 7)) * 8));
      }
#pragma unroll
      for (int ni = 0; ni < 4; ni++) {
        int row = wc * 64 + ni * 16 + l15;
        bfr[ni] = *(const bf16x8*)(Bs + row * 64 + (((ks * 4 + g) ^ (row & 7)) * 8));
      }
#pragma unroll
      for (int mi = 0; mi < 4; mi++)
#pragma unroll
        for (int ni = 0; ni < 4; ni++)
          acc[mi][ni] = __builtin_amdgcn_mfma_f32_16x16x32_bf16(af[mi], bfr[ni], acc[mi][ni], 0, 0, 0);
    }
  }

  const float* bias = (w == 0) ? bq : (w == 1) ? bk : bv;
  float mult = (w == 0) ? SCALE_ * LOG2E_ : 1.0f;  // fold scale*log2e into Q
  if (w == 2) {
    // V: write transposed Vt[bh][d][s], 8B stores (4 consecutive s per lane)
    ushort_t* Vout = QKV + 16777216u;
#pragma unroll
    for (int ni = 0; ni < 4; ++ni) {
      int n_col = n_base + wc * 64 + ni * 16 + l15;
      float bb = bias[n_col];
      int hh = n_col >> 6, d = n_col & 63;
#pragma unroll
      for (int mi = 0; mi < 4; ++mi) {
        int m_row = m_base + wr * 64 + mi * 16 + g * 4;
        int bbi = m_row >> 11, s = m_row & 2047;
        us4 o;
#pragma unroll
        for (int reg = 0; reg < 4; ++reg) o[reg] = f2bf(acc[mi][ni][reg] + bb);
        *(us4*)(Vout + ((size_t)((bbi * 16 + hh) * 64 + d)) * 2048 + s) = o;
      }
    }
  } else {
    ushort_t* out = QKV + (size_t)w * (8192u * 1024u);
#pragma unroll
    for (int ni = 0; ni < 4; ++ni) {
      int n_col = n_base + wc * 64 + ni * 16 + l15;
      float bb = bias[n_col];
#pragma unroll
      for (int mi = 0; mi < 4; ++mi) {
        int m_row = m_base + wr * 64 + mi * 16 + g * 4;
#pragma unroll
        for (int reg = 0; reg < 4; ++reg) {
          float v = (acc[mi][ni][reg] + bb) * mult;
          out[(size_t)(m_row + reg) * H_ + n_col] = f2bf(v);
        }
      }
    }
  }
}

// ---------------- flash attention, zero-P-LDS form -------------------
// Round-5: 512 thr = 8 waves x 32 q rows (was 4 waves x 64). Same grid
// 8x64, same per-CU staging and LDS (32 KB, 2 blocks/CU), but residency
// 2 -> 4 waves/SIMD so the S-MFMA -> exp2 -> pack -> PV chain of one
// wave overlaps another wave's opposite phase (m114 cross-wave overlap).
// Per-wave state halves (of[2][4], qf[2][2], lacc[2]) -> VGPR fits 128.
// Staging: 1 K-chunk + 1 V-chunk per thread per tile; counted vmcnt(2).
// S^T via two interleaved-row MFMAs per 16-key group; P stays in regs.
// K staged with sigma_K(s)=((s>>3)&1)*4+(s&3); V with sigma_V(s)=s&7.
// Row-sum via ones-MFMA (lsum on the matrix pipe; no epilogue shfl).
__global__ __launch_bounds__(512, 4) void attn(const ushort_t* __restrict__ QKV,
                                               const ushort_t* __restrict__ Vt,
                                               float* __restrict__ out) {
  __shared__ __align__(16) ushort_t Ks[2][64 * 64];   // 16 KB
  __shared__ __align__(16) ushort_t Vs[2][64 * 64];   // 16 KB
  int qt = blockIdx.x;   // 0..7
  int bh = blockIdx.y;   // 0..63
  int b = bh >> 4, h = bh & 15;
  int tid = threadIdx.x, lane = tid & 63, wave = tid >> 6;  // wave 0..7
  int g = lane >> 4, l15 = lane & 15;

  const ushort_t* Qb = QKV;
  const ushort_t* Kb = QKV + 8388608u;

  // Q B-frags: 32 q rows per wave (scale*log2e pre-folded into Q)
  bf16x8 qf[2][2];
#pragma unroll
  for (int mi = 0; mi < 2; ++mi) {
    int q_row = qt * 256 + wave * 32 + mi * 16 + l15;
    size_t qoff = (size_t)(b * S_ + q_row) * H_ + h * HD_;
    qf[mi][0] = *(const bf16x8*)(Qb + qoff + g * 8);
    qf[mi][1] = *(const bf16x8*)(Qb + qoff + 32 + g * 8);
  }

  // all-ones A-fragment for the row-sum MFMA (bit pattern 0x3F80 = bf16 1.0)
  union { us8 u; bf16x8 v; } ones_u;
#pragma unroll
  for (int i = 0; i < 8; ++i) ones_u.u[i] = 0x3F80;
  bf16x8 onesf = ones_u.v;

  f32x4 of[2][4];
  f32x4 lacc[2];
#pragma unroll
  for (int mi = 0; mi < 2; mi++) {
    lacc[mi] = (f32x4){0.f, 0.f, 0.f, 0.f};
#pragma unroll
    for (int ni = 0; ni < 4; ni++) of[mi][ni] = (f32x4){0.f, 0.f, 0.f, 0.f};
  }

  // interleaved A-row for S^T: row_a = kk*32 + (l15>>2)*8 + (l15&3), row_b = +4
  int ra = (l15 >> 2) * 8 + (l15 & 3);
  int sKa = ((l15 >> 2) & 1) * 4 + (l15 & 3);   // sigma_K of both rows
  int posK0 = (g ^ sKa) * 8, posK1 = ((4 + g) ^ sKa) * 8;

  // staging: 512 threads x 1 chunk per 8KB tile (K and V each)
  int ch = tid;                    // 0..511
  int s0 = ch >> 3;
  int cK = (ch & 7) ^ ((((s0 >> 3) & 1) << 2) | (s0 & 3));
  int cV = (ch & 7) ^ (s0 & 7);
  const ushort_t* srcK = Kb + (size_t)(b * S_ + s0) * H_ + h * HD_ + cK * 8;
  const ushort_t* srcV = Vt + ((size_t)bh * 64 + s0) * S_ + cV * 8;

  // preload tile 0
  async16(srcK, Ks[0] + ch * 8);
  async16(srcV, Vs[0] + ch * 8);

  for (int kb = 0; kb < 32; ++kb) {
    int cur = kb & 1, nxt = cur ^ 1;
    __syncthreads();                    // all waves done reading buf[nxt]
    if (kb < 31) {
      async16(srcK + (size_t)(kb + 1) * 64 * H_, Ks[nxt] + ch * 8);
      async16(srcV + (size_t)(kb + 1) * 64, Vs[nxt] + ch * 8);
      __builtin_amdgcn_s_waitcnt(0xF72);   // vmcnt(2): tile kb landed
    } else {
      __builtin_amdgcn_s_waitcnt(0xF70);   // vmcnt(0)
    }
    __syncthreads();                    // publish tile kb
    const ushort_t* Kc = Ks[cur];
    const ushort_t* Vc = Vs[cur];

#pragma unroll
    for (int kk = 0; kk < 2; ++kk) {
      int rowa = kk * 32 + ra;
      int rowb = rowa + 4;
      bf16x8 ka0 = *(const bf16x8*)(Kc + rowa * 64 + posK0);
      bf16x8 ka1 = *(const bf16x8*)(Kc + rowa * 64 + posK1);
      bf16x8 kb0 = *(const bf16x8*)(Kc + rowb * 64 + posK0);
      bf16x8 kb1 = *(const bf16x8*)(Kc + rowb * 64 + posK1);
      bf16x8 vf[4];
#pragma unroll
      for (int ni = 0; ni < 4; ++ni) {
        int row = ni * 16 + l15;
        vf[ni] = *(const bf16x8*)(Vc + row * 64 + (((kk * 4 + g) ^ (row & 7)) * 8));
      }
#pragma unroll
      for (int mi = 0; mi < 2; ++mi) {
        f32x4 sa = (f32x4){0.f, 0.f, 0.f, 0.f};
        f32x4 sb = (f32x4){0.f, 0.f, 0.f, 0.f};
        sa = __builtin_amdgcn_mfma_f32_16x16x32_bf16(ka0, qf[mi][0], sa, 0, 0, 0);
        sa = __builtin_amdgcn_mfma_f32_16x16x32_bf16(ka1, qf[mi][1], sa, 0, 0, 0);
        sb = __builtin_amdgcn_mfma_f32_16x16x32_bf16(kb0, qf[mi][0], sb, 0, 0, 0);
        sb = __builtin_amdgcn_mfma_f32_16x16x32_bf16(kb1, qf[mi][1], sb, 0, 0, 0);
        float pa0 = __builtin_amdgcn_exp2f(sa[0]);
        float pa1 = __builtin_amdgcn_exp2f(sa[1]);
        float pa2 = __builtin_amdgcn_exp2f(sa[2]);
        float pa3 = __builtin_amdgcn_exp2f(sa[3]);
        float pb0 = __builtin_amdgcn_exp2f(sb[0]);
        float pb1 = __builtin_amdgcn_exp2f(sb[1]);
        float pb2 = __builtin_amdgcn_exp2f(sb[2]);
        float pb3 = __builtin_amdgcn_exp2f(sb[3]);
        union { bf16x8 v; unsigned int u[4]; } pf;
        pf.u[0] = __builtin_amdgcn_perm(__float_as_uint(pa1) + 0x8000u,
                                        __float_as_uint(pa0) + 0x8000u, 0x07060302u);
        pf.u[1] = __builtin_amdgcn_perm(__float_as_uint(pa3) + 0x8000u,
                                        __float_as_uint(pa2) + 0x8000u, 0x07060302u);
        pf.u[2] = __builtin_amdgcn_perm(__float_as_uint(pb1) + 0x8000u,
                                        __float_as_uint(pb0) + 0x8000u, 0x07060302u);
        pf.u[3] = __builtin_amdgcn_perm(__float_as_uint(pb3) + 0x8000u,
                                        __float_as_uint(pb2) + 0x8000u, 0x07060302u);
#pragma unroll
        for (int ni = 0; ni < 4; ++ni)
          of[mi][ni] = __builtin_amdgcn_mfma_f32_16x16x32_bf16(vf[ni], pf.v, of[mi][ni], 0, 0, 0);
        // row-sum on the matrix pipe: lacc[mi][*] = sum_k P[k][q=l15]
        lacc[mi] = __builtin_amdgcn_mfma_f32_16x16x32_bf16(onesf, pf.v, lacc[mi], 0, 0, 0);
      }
    }
  }

  // ---- epilogue: O^T / l, float4 stores (no shfl: lacc holds full sum) ----
#pragma unroll
  for (int mi = 0; mi < 2; ++mi) {
    float inv = 1.0f / lacc[mi][0];
    int qglob = qt * 256 + wave * 32 + mi * 16 + l15;
    float* obase = out + (size_t)(b * S_ + qglob) * H_ + h * HD_ + g * 4;
#pragma unroll
    for (int ni = 0; ni < 4; ++ni) {
      float4 vv;
      vv.x = of[mi][ni][0] * inv;
      vv.y = of[mi][ni][1] * inv;
      vv.z = of[mi][ni][2] * inv;
      vv.w = of[mi][ni][3] * inv;
      *(float4*)(obase + ni * 16) = vv;
    }
  }
}

extern "C" void kernel_launch(void* const* d_in, const int* in_sizes, int n_in,
                              void* d_out, int out_size, void* d_ws, size_t ws_size,
                              hipStream_t stream) {
  const float* hs = (const float*)d_in[0];
  const float* Wq = (const float*)d_in[1];
  const float* bq = (const float*)d_in[2];
  const float* Wk = (const float*)d_in[3];
  const float* bk = (const float*)d_in[4];
  const float* Wv = (const float*)d_in[5];
  const float* bv = (const float*)d_in[6];
  float* out = (float*)d_out;

  // ws (bf16): Xb[8M] | Wt[3M] | QKV[24M]; V slot holds Vt[bh][d][s].
  ushort_t* Xb  = (ushort_t*)d_ws;
  ushort_t* Wt  = Xb + 8388608u;
  ushort_t* QKV = Wt + 3145728u;
  ushort_t* Vtp = QKV + 16777216u;

  conv_x<<<8192, 256, 0, stream>>>((const float4*)hs, Xb);
  conv_w<<<768, 256, 0, stream>>>(Wq, Wk, Wv, Wt);
  qkv_gemm<<<dim3(24, 64), 256, 0, stream>>>(Xb, Wt, bq, bk, bv, QKV);
  attn<<<dim3(8, 64), 512, 0, stream>>>(QKV, Vtp, out);
}

// Round 6
// 234.894 us; speedup vs baseline: 1.0352x; 1.0352x over previous
//
#include <hip/hip_runtime.h>
#include <hip/hip_bf16.h>
#include <stdint.h>

#define B_ 4
#define S_ 2048
#define H_ 1024
#define NH_ 16
#define HD_ 64
#define SCALE_ 0.125f
#define LOG2E_ 1.4426950408889634f

typedef __bf16 bf16x8 __attribute__((ext_vector_type(8)));
typedef float f32x4 __attribute__((ext_vector_type(4)));
typedef unsigned short us4 __attribute__((ext_vector_type(4)));
typedef unsigned short us8 __attribute__((ext_vector_type(8)));
typedef unsigned short ushort_t;

__device__ __forceinline__ ushort_t f2bf(float f) {
  union { float f; uint32_t u; } a; a.f = f;
  uint32_t r = (a.u + 0x7fffu + ((a.u >> 16) & 1u)) >> 16;
  return (ushort_t)r;
}

__device__ __forceinline__ void async16(const void* g, void* l) {
  __builtin_amdgcn_global_load_lds(
      (const __attribute__((address_space(1))) unsigned int*)(uintptr_t)g,
      (__attribute__((address_space(3))) unsigned int*)(uintptr_t)l, 16, 0, 0);
}

// raw workgroup barrier: no implicit vmcnt/lgkmcnt drain (unlike
// __syncthreads, which drains the global_load_lds queue - m97's ~20% stall).
// "memory" clobber stops the compiler moving LDS/VMEM ops across it.
__device__ __forceinline__ void raw_barrier() {
  asm volatile("s_barrier" ::: "memory");
}

// ---------------- convert hidden_states fp32 -> bf16 ----------------
__global__ __launch_bounds__(256) void conv_x(const float4* __restrict__ x,
                                              ushort_t* __restrict__ xb) {
  int i = blockIdx.x * 256 + threadIdx.x;
  float4 v = x[i];
  us4 o;
  o.x = f2bf(v.x); o.y = f2bf(v.y); o.z = f2bf(v.z); o.w = f2bf(v.w);
  *(us4*)(xb + (size_t)i * 4) = o;
}

// ------- conv+transpose W[k][n] -> Wt[w][n][k], LDS-tiled 64x64 ------
__global__ __launch_bounds__(256) void conv_w(const float* __restrict__ Wq,
                                              const float* __restrict__ Wk,
                                              const float* __restrict__ Wv,
                                              ushort_t* __restrict__ Wt) {
  __shared__ __align__(16) ushort_t T[64 * 64];
  int bid = blockIdx.x;            // 0..767
  int w = bid >> 8;
  int t2 = bid & 255;
  int kt = (t2 >> 4) * 64, nt = (t2 & 15) * 64;
  const float* W = (w == 0) ? Wq : (w == 1) ? Wk : Wv;
  int tid = threadIdx.x;
  int k = tid >> 2, nq = tid & 3;
#pragma unroll
  for (int j4 = 0; j4 < 4; ++j4) {
    int n = nq * 4 + j4 * 16;
    float4 f = *(const float4*)(W + (size_t)(kt + k) * H_ + nt + n);
    us4 o;
    o.x = f2bf(f.x); o.y = f2bf(f.y); o.z = f2bf(f.z); o.w = f2bf(f.w);
    *(us4*)(T + k * 64 + (((n >> 3) ^ (k & 7)) * 8) + (n & 7)) = o;
  }
  __syncthreads();
  int n2 = tid >> 2, kq = tid & 3;
  us8 o0, o1;
#pragma unroll
  for (int j = 0; j < 16; ++j) {
    int kk = kq * 16 + j;
    ushort_t v = T[kk * 64 + (((n2 >> 3) ^ (kk & 7)) * 8) + (n2 & 7)];
    if (j < 8) o0[j] = v; else o1[j - 8] = v;
  }
  size_t obase = (size_t)w * (H_ * H_) + (size_t)(nt + n2) * H_ + kt + kq * 16;
  *(us8*)(Wt + obase) = o0;
  *(us8*)(Wt + obase + 8) = o1;
}

// ---------------- fused QKV GEMM (BK=64 + T3 single-barrier dbuf) ----
// Round-6: round-4's winning compute (BK=64, XOR-8 swizzle, conflicts=0)
// with the T3 recipe loop: {stage tile t+1 -> other buffer; compute tile
// t; vmcnt(0); raw barrier}. Stage-issue is separated from its drain by
// the whole 32-MFMA compute phase, and the raw barrier does NOT re-drain
// (unlike __syncthreads). Buffers touched in one segment are disjoint
// (write buf^1, read buf) -> race-free under wave skew.
// w==2 (V) epilogue writes transposed [bh][d][s] into the V slot so attn
// can stage V^T directly.
__global__ __launch_bounds__(256) void qkv_gemm(const ushort_t* __restrict__ Xb,
                                                const ushort_t* __restrict__ Wt,
                                                const float* __restrict__ bq,
                                                const float* __restrict__ bk,
                                                const float* __restrict__ bv,
                                                ushort_t* __restrict__ QKV) {
  __shared__ __align__(16) ushort_t As0[128 * 64];   // 16 KB
  __shared__ __align__(16) ushort_t As1[128 * 64];   // 16 KB
  __shared__ __align__(16) ushort_t Bs0[128 * 64];   // 16 KB
  __shared__ __align__(16) ushort_t Bs1[128 * 64];   // 16 KB
  int nb = blockIdx.x;             // 0..23
  int mb = blockIdx.y;             // 0..63
  int w = nb >> 3;
  int n_base = (nb & 7) * 128;
  int m_base = mb * 128;
  const ushort_t* Wtw = Wt + (size_t)w * (H_ * H_);
  int tid = threadIdx.x;
  int lane = tid & 63, wave = tid >> 6;
  int wr = wave >> 1, wc = wave & 1;
  int g = lane >> 4, l15 = lane & 15;

  f32x4 acc[4][4];
#pragma unroll
  for (int i = 0; i < 4; i++)
#pragma unroll
    for (int j = 0; j < 4; j++) acc[i][j] = (f32x4){0.f, 0.f, 0.f, 0.f};

  // staging: 8 chunks/thread/iter (4 for A, 4 for B). chunk id = tid+it*256
  // -> (row = id>>3, slot = id&7); rows step by 32 per it (low 3 bits of
  // row invariant -> one source-column xor per thread).
  int r0 = tid >> 3, sl = tid & 7;
  int cc = sl ^ (r0 & 7);
  const ushort_t* sA = Xb + (size_t)(m_base + r0) * H_ + cc * 8;
  const ushort_t* sB = Wtw + (size_t)(n_base + r0) * H_ + cc * 8;
  int la = tid * 8;                // ushort offset of chunk id (it adds 2048)

  // prologue: stage tile 0, publish
#pragma unroll
  for (int it = 0; it < 4; ++it) {
    async16(sA + (size_t)it * 32 * H_, As0 + la + it * 2048);
    async16(sB + (size_t)it * 32 * H_, Bs0 + la + it * 2048);
  }
  __builtin_amdgcn_s_waitcnt(0xF70);   // vmcnt(0)
  raw_barrier();

  for (int kt = 0; kt < 16; ++kt) {
    const ushort_t* Ac = (kt & 1) ? As1 : As0;
    const ushort_t* Bc = (kt & 1) ? Bs1 : Bs0;
    ushort_t* An = (kt & 1) ? As0 : As1;
    ushort_t* Bn = (kt & 1) ? Bs0 : Bs1;
    if (kt < 15) {
      int k0 = (kt + 1) * 64;
#pragma unroll
      for (int it = 0; it < 4; ++it) {
        async16(sA + (size_t)it * 32 * H_ + k0, An + la + it * 2048);
        async16(sB + (size_t)it * 32 * H_ + k0, Bn + la + it * 2048);
      }
    }

#pragma unroll
    for (int ks = 0; ks < 2; ++ks) {
      bf16x8 af[4], bfr[4];
#pragma unroll
      for (int mi = 0; mi < 4; mi++) {
        int row = wr * 64 + mi * 16 + l15;
        af[mi] = *(const bf16x8*)(Ac + row * 64 + (((ks * 4 + g) ^ (row & 7)) * 8));
      }
#pragma unroll
      for (int ni = 0; ni < 4; ni++) {
        int row = wc * 64 + ni * 16 + l15;
        bfr[ni] = *(const bf16x8*)(Bc + row * 64 + (((ks * 4 + g) ^ (row & 7)) * 8));
      }
#pragma unroll
      for (int mi = 0; mi < 4; mi++)
#pragma unroll
        for (int ni = 0; ni < 4; ni++)
          acc[mi][ni] = __builtin_amdgcn_mfma_f32_16x16x32_bf16(af[mi], bfr[ni], acc[mi][ni], 0, 0, 0);
    }

    if (kt < 15) {
      __builtin_amdgcn_s_waitcnt(0xF70);   // vmcnt(0): tile kt+1 landed
      raw_barrier();                       // publish; no re-drain
    }
  }

  const float* bias = (w == 0) ? bq : (w == 1) ? bk : bv;
  float mult = (w == 0) ? SCALE_ * LOG2E_ : 1.0f;  // fold scale*log2e into Q
  if (w == 2) {
    // V: write transposed Vt[bh][d][s], 8B stores (4 consecutive s per lane)
    ushort_t* Vout = QKV + 16777216u;
#pragma unroll
    for (int ni = 0; ni < 4; ++ni) {
      int n_col = n_base + wc * 64 + ni * 16 + l15;
      float bb = bias[n_col];
      int hh = n_col >> 6, d = n_col & 63;
#pragma unroll
      for (int mi = 0; mi < 4; ++mi) {
        int m_row = m_base + wr * 64 + mi * 16 + g * 4;
        int bbi = m_row >> 11, s = m_row & 2047;
        us4 o;
#pragma unroll
        for (int reg = 0; reg < 4; ++reg) o[reg] = f2bf(acc[mi][ni][reg] + bb);
        *(us4*)(Vout + ((size_t)((bbi * 16 + hh) * 64 + d)) * 2048 + s) = o;
      }
    }
  } else {
    ushort_t* out = QKV + (size_t)w * (8192u * 1024u);
#pragma unroll
    for (int ni = 0; ni < 4; ++ni) {
      int n_col = n_base + wc * 64 + ni * 16 + l15;
      float bb = bias[n_col];
#pragma unroll
      for (int mi = 0; mi < 4; ++mi) {
        int m_row = m_base + wr * 64 + mi * 16 + g * 4;
#pragma unroll
        for (int reg = 0; reg < 4; ++reg) {
          float v = (acc[mi][ni][reg] + bb) * mult;
          out[(size_t)(m_row + reg) * H_ + n_col] = f2bf(v);
        }
      }
    }
  }
}

// ---------------- flash attention, zero-P-LDS form -------------------
// Round-6: identical structure to round 5 (8 waves x 32 q, dbuf K/V,
// counted vmcnt(2)) but both __syncthreads -> raw s_barrier. The old
// __syncthreads drained vmcnt(0) (global_load_lds pending), nullifying
// the counted prefetch; now tile k+1 loads stay in flight across both
// barriers for a full iteration. Race audit: stage writes buf[nxt] only
// after the top barrier; all ds_reads of buf[nxt] from iter k-1 were
// data-consumed by MFMAs (lgkm drained by use) before that barrier.
// S^T via two interleaved-row MFMAs per 16-key group; P stays in regs.
// K staged with sigma_K(s)=((s>>3)&1)*4+(s&3); V with sigma_V(s)=s&7.
// Row-sum via ones-MFMA (lsum on the matrix pipe; no epilogue shfl).
__global__ __launch_bounds__(512, 4) void attn(const ushort_t* __restrict__ QKV,
                                               const ushort_t* __restrict__ Vt,
                                               float* __restrict__ out) {
  __shared__ __align__(16) ushort_t Ks[2][64 * 64];   // 16 KB
  __shared__ __align__(16) ushort_t Vs[2][64 * 64];   // 16 KB
  int qt = blockIdx.x;   // 0..7
  int bh = blockIdx.y;   // 0..63
  int b = bh >> 4, h = bh & 15;
  int tid = threadIdx.x, lane = tid & 63, wave = tid >> 6;  // wave 0..7
  int g = lane >> 4, l15 = lane & 15;

  const ushort_t* Qb = QKV;
  const ushort_t* Kb = QKV + 8388608u;

  // Q B-frags: 32 q rows per wave (scale*log2e pre-folded into Q)
  bf16x8 qf[2][2];
#pragma unroll
  for (int mi = 0; mi < 2; ++mi) {
    int q_row = qt * 256 + wave * 32 + mi * 16 + l15;
    size_t qoff = (size_t)(b * S_ + q_row) * H_ + h * HD_;
    qf[mi][0] = *(const bf16x8*)(Qb + qoff + g * 8);
    qf[mi][1] = *(const bf16x8*)(Qb + qoff + 32 + g * 8);
  }

  // all-ones A-fragment for the row-sum MFMA (bit pattern 0x3F80 = bf16 1.0)
  union { us8 u; bf16x8 v; } ones_u;
#pragma unroll
  for (int i = 0; i < 8; ++i) ones_u.u[i] = 0x3F80;
  bf16x8 onesf = ones_u.v;

  f32x4 of[2][4];
  f32x4 lacc[2];
#pragma unroll
  for (int mi = 0; mi < 2; mi++) {
    lacc[mi] = (f32x4){0.f, 0.f, 0.f, 0.f};
#pragma unroll
    for (int ni = 0; ni < 4; ni++) of[mi][ni] = (f32x4){0.f, 0.f, 0.f, 0.f};
  }

  // interleaved A-row for S^T: row_a = kk*32 + (l15>>2)*8 + (l15&3), row_b = +4
  int ra = (l15 >> 2) * 8 + (l15 & 3);
  int sKa = ((l15 >> 2) & 1) * 4 + (l15 & 3);   // sigma_K of both rows
  int posK0 = (g ^ sKa) * 8, posK1 = ((4 + g) ^ sKa) * 8;

  // staging: 512 threads x 1 chunk per 8KB tile (K and V each)
  int ch = tid;                    // 0..511
  int s0 = ch >> 3;
  int cK = (ch & 7) ^ ((((s0 >> 3) & 1) << 2) | (s0 & 3));
  int cV = (ch & 7) ^ (s0 & 7);
  const ushort_t* srcK = Kb + (size_t)(b * S_ + s0) * H_ + h * HD_ + cK * 8;
  const ushort_t* srcV = Vt + ((size_t)bh * 64 + s0) * S_ + cV * 8;

  // preload tile 0
  async16(srcK, Ks[0] + ch * 8);
  async16(srcV, Vs[0] + ch * 8);

  for (int kb = 0; kb < 32; ++kb) {
    int cur = kb & 1, nxt = cur ^ 1;
    raw_barrier();                      // all waves done reading buf[nxt]
    if (kb < 31) {
      async16(srcK + (size_t)(kb + 1) * 64 * H_, Ks[nxt] + ch * 8);
      async16(srcV + (size_t)(kb + 1) * 64, Vs[nxt] + ch * 8);
      __builtin_amdgcn_s_waitcnt(0xF72);   // vmcnt(2): tile kb landed
    } else {
      __builtin_amdgcn_s_waitcnt(0xF70);   // vmcnt(0)
    }
    raw_barrier();                      // publish tile kb (no re-drain)
    const ushort_t* Kc = Ks[cur];
    const ushort_t* Vc = Vs[cur];

#pragma unroll
    for (int kk = 0; kk < 2; ++kk) {
      int rowa = kk * 32 + ra;
      int rowb = rowa + 4;
      bf16x8 ka0 = *(const bf16x8*)(Kc + rowa * 64 + posK0);
      bf16x8 ka1 = *(const bf16x8*)(Kc + rowa * 64 + posK1);
      bf16x8 kb0 = *(const bf16x8*)(Kc + rowb * 64 + posK0);
      bf16x8 kb1 = *(const bf16x8*)(Kc + rowb * 64 + posK1);
      bf16x8 vf[4];
#pragma unroll
      for (int ni = 0; ni < 4; ++ni) {
        int row = ni * 16 + l15;
        vf[ni] = *(const bf16x8*)(Vc + row * 64 + (((kk * 4 + g) ^ (row & 7)) * 8));
      }
#pragma unroll
      for (int mi = 0; mi < 2; ++mi) {
        f32x4 sa = (f32x4){0.f, 0.f, 0.f, 0.f};
        f32x4 sb = (f32x4){0.f, 0.f, 0.f, 0.f};
        sa = __builtin_amdgcn_mfma_f32_16x16x32_bf16(ka0, qf[mi][0], sa, 0, 0, 0);
        sa = __builtin_amdgcn_mfma_f32_16x16x32_bf16(ka1, qf[mi][1], sa, 0, 0, 0);
        sb = __builtin_amdgcn_mfma_f32_16x16x32_bf16(kb0, qf[mi][0], sb, 0, 0, 0);
        sb = __builtin_amdgcn_mfma_f32_16x16x32_bf16(kb1, qf[mi][1], sb, 0, 0, 0);
        float pa0 = __builtin_amdgcn_exp2f(sa[0]);
        float pa1 = __builtin_amdgcn_exp2f(sa[1]);
        float pa2 = __builtin_amdgcn_exp2f(sa[2]);
        float pa3 = __builtin_amdgcn_exp2f(sa[3]);
        float pb0 = __builtin_amdgcn_exp2f(sb[0]);
        float pb1 = __builtin_amdgcn_exp2f(sb[1]);
        float pb2 = __builtin_amdgcn_exp2f(sb[2]);
        float pb3 = __builtin_amdgcn_exp2f(sb[3]);
        union { bf16x8 v; unsigned int u[4]; } pf;
        pf.u[0] = __builtin_amdgcn_perm(__float_as_uint(pa1) + 0x8000u,
                                        __float_as_uint(pa0) + 0x8000u, 0x07060302u);
        pf.u[1] = __builtin_amdgcn_perm(__float_as_uint(pa3) + 0x8000u,
                                        __float_as_uint(pa2) + 0x8000u, 0x07060302u);
        pf.u[2] = __builtin_amdgcn_perm(__float_as_uint(pb1) + 0x8000u,
                                        __float_as_uint(pb0) + 0x8000u, 0x07060302u);
        pf.u[3] = __builtin_amdgcn_perm(__float_as_uint(pb3) + 0x8000u,
                                        __float_as_uint(pb2) + 0x8000u, 0x07060302u);
#pragma unroll
        for (int ni = 0; ni < 4; ++ni)
          of[mi][ni] = __builtin_amdgcn_mfma_f32_16x16x32_bf16(vf[ni], pf.v, of[mi][ni], 0, 0, 0);
        // row-sum on the matrix pipe: lacc[mi][*] = sum_k P[k][q=l15]
        lacc[mi] = __builtin_amdgcn_mfma_f32_16x16x32_bf16(onesf, pf.v, lacc[mi], 0, 0, 0);
      }
    }
  }

  // ---- epilogue: O^T / l, float4 stores (no shfl: lacc holds full sum) ----
#pragma unroll
  for (int mi = 0; mi < 2; ++mi) {
    float inv = 1.0f / lacc[mi][0];
    int qglob = qt * 256 + wave * 32 + mi * 16 + l15;
    float* obase = out + (size_t)(b * S_ + qglob) * H_ + h * HD_ + g * 4;
#pragma unroll
    for (int ni = 0; ni < 4; ++ni) {
      float4 vv;
      vv.x = of[mi][ni][0] * inv;
      vv.y = of[mi][ni][1] * inv;
      vv.z = of[mi][ni][2] * inv;
      vv.w = of[mi][ni][3] * inv;
      *(float4*)(obase + ni * 16) = vv;
    }
  }
}

extern "C" void kernel_launch(void* const* d_in, const int* in_sizes, int n_in,
                              void* d_out, int out_size, void* d_ws, size_t ws_size,
                              hipStream_t stream) {
  const float* hs = (const float*)d_in[0];
  const float* Wq = (const float*)d_in[1];
  const float* bq = (const float*)d_in[2];
  const float* Wk = (const float*)d_in[3];
  const float* bk = (const float*)d_in[4];
  const float* Wv = (const float*)d_in[5];
  const float* bv = (const float*)d_in[6];
  float* out = (float*)d_out;

  // ws (bf16): Xb[8M] | Wt[3M] | QKV[24M]; V slot holds Vt[bh][d][s].
  ushort_t* Xb  = (ushort_t*)d_ws;
  ushort_t* Wt  = Xb + 8388608u;
  ushort_t* QKV = Wt + 3145728u;
  ushort_t* Vtp = QKV + 16777216u;

  conv_x<<<8192, 256, 0, stream>>>((const float4*)hs, Xb);
  conv_w<<<768, 256, 0, stream>>>(Wq, Wk, Wv, Wt);
  qkv_gemm<<<dim3(24, 64), 256, 0, stream>>>(Xb, Wt, bq, bk, bv, QKV);
  attn<<<dim3(8, 64), 512, 0, stream>>>(QKV, Vtp, out);
}

// Round 9
// 233.376 us; speedup vs baseline: 1.0419x; 1.0065x over previous
//
#include <hip/hip_runtime.h>
#include <hip/hip_bf16.h>
#include <stdint.h>

#define B_ 4
#define S_ 2048
#define H_ 1024
#define NH_ 16
#define HD_ 64
#define SCALE_ 0.125f
#define LOG2E_ 1.4426950408889634f

typedef __bf16 bf16x8 __attribute__((ext_vector_type(8)));
typedef float f32x4 __attribute__((ext_vector_type(4)));
typedef unsigned short us4 __attribute__((ext_vector_type(4)));
typedef unsigned short us8 __attribute__((ext_vector_type(8)));
typedef unsigned short ushort_t;

__device__ __forceinline__ ushort_t f2bf(float f) {
  union { float f; uint32_t u; } a; a.f = f;
  uint32_t r = (a.u + 0x7fffu + ((a.u >> 16) & 1u)) >> 16;
  return (ushort_t)r;
}

__device__ __forceinline__ void async16(const void* g, void* l) {
  __builtin_amdgcn_global_load_lds(
      (const __attribute__((address_space(1))) unsigned int*)(uintptr_t)g,
      (__attribute__((address_space(3))) unsigned int*)(uintptr_t)l, 16, 0, 0);
}

// raw workgroup barrier: no implicit vmcnt/lgkmcnt drain (unlike
// __syncthreads, which drains the global_load_lds queue - m97's ~20% stall).
// "memory" clobber stops the compiler moving LDS/VMEM ops across it.
__device__ __forceinline__ void raw_barrier() {
  asm volatile("s_barrier" ::: "memory");
}

// ---------------- convert hidden_states fp32 -> bf16 ----------------
__global__ __launch_bounds__(256) void conv_x(const float4* __restrict__ x,
                                              ushort_t* __restrict__ xb) {
  int i = blockIdx.x * 256 + threadIdx.x;
  float4 v = x[i];
  us4 o;
  o.x = f2bf(v.x); o.y = f2bf(v.y); o.z = f2bf(v.z); o.w = f2bf(v.w);
  *(us4*)(xb + (size_t)i * 4) = o;
}

// ------- conv+transpose W[k][n] -> Wt[w][n][k], LDS-tiled 64x64 ------
__global__ __launch_bounds__(256) void conv_w(const float* __restrict__ Wq,
                                              const float* __restrict__ Wk,
                                              const float* __restrict__ Wv,
                                              ushort_t* __restrict__ Wt) {
  __shared__ __align__(16) ushort_t T[64 * 64];
  int bid = blockIdx.x;            // 0..767
  int w = bid >> 8;
  int t2 = bid & 255;
  int kt = (t2 >> 4) * 64, nt = (t2 & 15) * 64;
  const float* W = (w == 0) ? Wq : (w == 1) ? Wk : Wv;
  int tid = threadIdx.x;
  int k = tid >> 2, nq = tid & 3;
#pragma unroll
  for (int j4 = 0; j4 < 4; ++j4) {
    int n = nq * 4 + j4 * 16;
    float4 f = *(const float4*)(W + (size_t)(kt + k) * H_ + nt + n);
    us4 o;
    o.x = f2bf(f.x); o.y = f2bf(f.y); o.z = f2bf(f.z); o.w = f2bf(f.w);
    *(us4*)(T + k * 64 + (((n >> 3) ^ (k & 7)) * 8) + (n & 7)) = o;
  }
  __syncthreads();
  int n2 = tid >> 2, kq = tid & 3;
  us8 o0, o1;
#pragma unroll
  for (int j = 0; j < 16; ++j) {
    int kk = kq * 16 + j;
    ushort_t v = T[kk * 64 + (((n2 >> 3) ^ (kk & 7)) * 8) + (n2 & 7)];
    if (j < 8) o0[j] = v; else o1[j - 8] = v;
  }
  size_t obase = (size_t)w * (H_ * H_) + (size_t)(nt + n2) * H_ + kt + kq * 16;
  *(us8*)(Wt + obase) = o0;
  *(us8*)(Wt + obase + 8) = o1;
}

// ---------------- fused QKV GEMM (BK=64 + T3 single-barrier dbuf) ----
// Round-6 structure kept: BK=64, XOR-8 swizzle, raw-barrier dbuf loop.
// w==2 (V) epilogue writes transposed [bh][d][s] into the V slot so attn
// can stage V^T directly.
__global__ __launch_bounds__(256) void qkv_gemm(const ushort_t* __restrict__ Xb,
                                                const ushort_t* __restrict__ Wt,
                                                const float* __restrict__ bq,
                                                const float* __restrict__ bk,
                                                const float* __restrict__ bv,
                                                ushort_t* __restrict__ QKV) {
  __shared__ __align__(16) ushort_t As0[128 * 64];   // 16 KB
  __shared__ __align__(16) ushort_t As1[128 * 64];   // 16 KB
  __shared__ __align__(16) ushort_t Bs0[128 * 64];   // 16 KB
  __shared__ __align__(16) ushort_t Bs1[128 * 64];   // 16 KB
  int nb = blockIdx.x;             // 0..23
  int mb = blockIdx.y;             // 0..63
  int w = nb >> 3;
  int n_base = (nb & 7) * 128;
  int m_base = mb * 128;
  const ushort_t* Wtw = Wt + (size_t)w * (H_ * H_);
  int tid = threadIdx.x;
  int lane = tid & 63, wave = tid >> 6;
  int wr = wave >> 1, wc = wave & 1;
  int g = lane >> 4, l15 = lane & 15;

  f32x4 acc[4][4];
#pragma unroll
  for (int i = 0; i < 4; i++)
#pragma unroll
    for (int j = 0; j < 4; j++) acc[i][j] = (f32x4){0.f, 0.f, 0.f, 0.f};

  // staging: 8 chunks/thread/iter (4 for A, 4 for B). chunk id = tid+it*256
  // -> (row = id>>3, slot = id&7); rows step by 32 per it (low 3 bits of
  // row invariant -> one source-column xor per thread).
  int r0 = tid >> 3, sl = tid & 7;
  int cc = sl ^ (r0 & 7);
  const ushort_t* sA = Xb + (size_t)(m_base + r0) * H_ + cc * 8;
  const ushort_t* sB = Wtw + (size_t)(n_base + r0) * H_ + cc * 8;
  int la = tid * 8;                // ushort offset of chunk id (it adds 2048)

  // prologue: stage tile 0, publish
#pragma unroll
  for (int it = 0; it < 4; ++it) {
    async16(sA + (size_t)it * 32 * H_, As0 + la + it * 2048);
    async16(sB + (size_t)it * 32 * H_, Bs0 + la + it * 2048);
  }
  __builtin_amdgcn_s_waitcnt(0xF70);   // vmcnt(0)
  raw_barrier();

  for (int kt = 0; kt < 16; ++kt) {
    const ushort_t* Ac = (kt & 1) ? As1 : As0;
    const ushort_t* Bc = (kt & 1) ? Bs1 : Bs0;
    ushort_t* An = (kt & 1) ? As0 : As1;
    ushort_t* Bn = (kt & 1) ? Bs0 : Bs1;
    if (kt < 15) {
      int k0 = (kt + 1) * 64;
#pragma unroll
      for (int it = 0; it < 4; ++it) {
        async16(sA + (size_t)it * 32 * H_ + k0, An + la + it * 2048);
        async16(sB + (size_t)it * 32 * H_ + k0, Bn + la + it * 2048);
      }
    }

#pragma unroll
    for (int ks = 0; ks < 2; ++ks) {
      bf16x8 af[4], bfr[4];
#pragma unroll
      for (int mi = 0; mi < 4; mi++) {
        int row = wr * 64 + mi * 16 + l15;
        af[mi] = *(const bf16x8*)(Ac + row * 64 + (((ks * 4 + g) ^ (row & 7)) * 8));
      }
#pragma unroll
      for (int ni = 0; ni < 4; ni++) {
        int row = wc * 64 + ni * 16 + l15;
        bfr[ni] = *(const bf16x8*)(Bc + row * 64 + (((ks * 4 + g) ^ (row & 7)) * 8));
      }
#pragma unroll
      for (int mi = 0; mi < 4; mi++)
#pragma unroll
        for (int ni = 0; ni < 4; ni++)
          acc[mi][ni] = __builtin_amdgcn_mfma_f32_16x16x32_bf16(af[mi], bfr[ni], acc[mi][ni], 0, 0, 0);
    }

    if (kt < 15) {
      __builtin_amdgcn_s_waitcnt(0xF70);   // vmcnt(0): tile kt+1 landed
      raw_barrier();                       // publish; no re-drain
    }
  }

  const float* bias = (w == 0) ? bq : (w == 1) ? bk : bv;
  float mult = (w == 0) ? SCALE_ * LOG2E_ : 1.0f;  // fold scale*log2e into Q
  if (w == 2) {
    // V: write transposed Vt[bh][d][s], 8B stores (4 consecutive s per lane)
    ushort_t* Vout = QKV + 16777216u;
#pragma unroll
    for (int ni = 0; ni < 4; ++ni) {
      int n_col = n_base + wc * 64 + ni * 16 + l15;
      float bb = bias[n_col];
      int hh = n_col >> 6, d = n_col & 63;
#pragma unroll
      for (int mi = 0; mi < 4; ++mi) {
        int m_row = m_base + wr * 64 + mi * 16 + g * 4;
        int bbi = m_row >> 11, s = m_row & 2047;
        us4 o;
#pragma unroll
        for (int reg = 0; reg < 4; ++reg) o[reg] = f2bf(acc[mi][ni][reg] + bb);
        *(us4*)(Vout + ((size_t)((bbi * 16 + hh) * 64 + d)) * 2048 + s) = o;
      }
    }
  } else {
    ushort_t* out = QKV + (size_t)w * (8192u * 1024u);
#pragma unroll
    for (int ni = 0; ni < 4; ++ni) {
      int n_col = n_base + wc * 64 + ni * 16 + l15;
      float bb = bias[n_col];
#pragma unroll
      for (int mi = 0; mi < 4; ++mi) {
        int m_row = m_base + wr * 64 + mi * 16 + g * 4;
#pragma unroll
        for (int reg = 0; reg < 4; ++reg) {
          float v = (acc[mi][ni][reg] + bb) * mult;
          out[(size_t)(m_row + reg) * H_ + n_col] = f2bf(v);
        }
      }
    }
  }
}

// ---------------- flash attention, zero-P-LDS form -------------------
// Round-7 kernel, third submission (rounds 7/8 were broker failures; no
// kernel-side signal. Audited: uniform barriers, LDS 64 KB in budget,
// no OOB, constant trip counts). KVBLK 64->128: each tile covers 128
// keys (4 kk groups), halving per-block {barrier convoy, waitcnt, swap}
// events (64 -> 32 barriers) and doubling the compute window a
// tile-fetch can hide under. LDS 64 KB (2 blocks/CU). Staging: 4
// async16/thread/tile (2 K + 2 V), counted vmcnt(4).
// Bank math at the wider rows: row strides 128B/256B are 0 mod 32 banks
// so only the chunk-XOR spreads banks: K keeps sigma_K (invariant in kk;
// 8 bank-groups x 2 lanes = 2-way = free), V uses sigma_V(c)=c^(row&7)
// over 16 chunks (2-way = free). Global source pre-swizzled, LDS dest
// linear (G21 both-sides rule).
// S^T via two interleaved-row MFMAs per 16-key group; P stays in regs.
// Row-sum via ones-MFMA (lsum on the matrix pipe; no epilogue shfl).
__global__ __launch_bounds__(512, 4) void attn(const ushort_t* __restrict__ QKV,
                                               const ushort_t* __restrict__ Vt,
                                               float* __restrict__ out) {
  __shared__ __align__(16) ushort_t Ks[2][128 * 64];   // 32 KB
  __shared__ __align__(16) ushort_t Vs[2][64 * 128];   // 32 KB
  int qt = blockIdx.x;   // 0..7
  int bh = blockIdx.y;   // 0..63
  int b = bh >> 4, h = bh & 15;
  int tid = threadIdx.x, lane = tid & 63, wave = tid >> 6;  // wave 0..7
  int g = lane >> 4, l15 = lane & 15;

  const ushort_t* Qb = QKV;
  const ushort_t* Kb = QKV + 8388608u;

  // Q B-frags: 32 q rows per wave (scale*log2e pre-folded into Q)
  bf16x8 qf[2][2];
#pragma unroll
  for (int mi = 0; mi < 2; ++mi) {
    int q_row = qt * 256 + wave * 32 + mi * 16 + l15;
    size_t qoff = (size_t)(b * S_ + q_row) * H_ + h * HD_;
    qf[mi][0] = *(const bf16x8*)(Qb + qoff + g * 8);
    qf[mi][1] = *(const bf16x8*)(Qb + qoff + 32 + g * 8);
  }

  // all-ones A-fragment for the row-sum MFMA (bit pattern 0x3F80 = bf16 1.0)
  union { us8 u; bf16x8 v; } ones_u;
#pragma unroll
  for (int i = 0; i < 8; ++i) ones_u.u[i] = 0x3F80;
  bf16x8 onesf = ones_u.v;

  f32x4 of[2][4];
  f32x4 lacc[2];
#pragma unroll
  for (int mi = 0; mi < 2; mi++) {
    lacc[mi] = (f32x4){0.f, 0.f, 0.f, 0.f};
#pragma unroll
    for (int ni = 0; ni < 4; ni++) of[mi][ni] = (f32x4){0.f, 0.f, 0.f, 0.f};
  }

  // interleaved A-row for S^T: row_a = kk*32 + (l15>>2)*8 + (l15&3), row_b = +4
  // sigma_K depends only on row bits {0,1,3} -> invariant across kk and a/b.
  int ra = (l15 >> 2) * 8 + (l15 & 3);
  int sKa = ((l15 >> 2) & 1) * 4 + (l15 & 3);   // sigma_K of both rows
  int posK0 = (g ^ sKa) * 8, posK1 = ((4 + g) ^ sKa) * 8;

  // staging per 128-key tile: K = 1024 chunks (row=id>>3, slot=id&7),
  // V = 1024 chunks (row=id>>4, slot=id&15); ids {tid, tid+512}.
  int rK0 = tid >> 3, rK1 = rK0 + 64;      // (tid+512)>>3
  int slK = tid & 7;
  int cKa = slK ^ ((((rK0 >> 3) & 1) << 2) | (rK0 & 3));
  int cKb = slK ^ ((((rK1 >> 3) & 1) << 2) | (rK1 & 3));
  int rV0 = tid >> 4, rV1 = rV0 + 32;      // (tid+512)>>4
  int slV = tid & 15;
  int cV = slV ^ (rV0 & 7);                // rV1&7 == rV0&7
  const ushort_t* srcK0 = Kb + (size_t)(b * S_ + rK0) * H_ + h * HD_ + cKa * 8;
  const ushort_t* srcK1 = Kb + (size_t)(b * S_ + rK1) * H_ + h * HD_ + cKb * 8;
  const ushort_t* srcV0 = Vt + ((size_t)bh * 64 + rV0) * S_ + cV * 8;
  const ushort_t* srcV1 = Vt + ((size_t)bh * 64 + rV1) * S_ + cV * 8;
  int laK0 = tid * 8, laK1 = (tid + 512) * 8;  // linear LDS dests

  // preload tile 0
  async16(srcK0, Ks[0] + laK0);
  async16(srcK1, Ks[0] + laK1);
  async16(srcV0, Vs[0] + laK0);
  async16(srcV1, Vs[0] + laK1);

  for (int kb = 0; kb < 16; ++kb) {
    int cur = kb & 1, nxt = cur ^ 1;
    raw_barrier();                      // all waves done reading buf[nxt]
    if (kb < 15) {
      size_t koff = (size_t)(kb + 1) * 128 * H_;
      int voff = (kb + 1) * 128;
      async16(srcK0 + koff, Ks[nxt] + laK0);
      async16(srcK1 + koff, Ks[nxt] + laK1);
      async16(srcV0 + voff, Vs[nxt] + laK0);
      async16(srcV1 + voff, Vs[nxt] + laK1);
      __builtin_amdgcn_s_waitcnt(0xF74);   // vmcnt(4): tile kb landed
    } else {
      __builtin_amdgcn_s_waitcnt(0xF70);   // vmcnt(0)
    }
    raw_barrier();                      // publish tile kb (no re-drain)
    const ushort_t* Kc = Ks[cur];
    const ushort_t* Vc = Vs[cur];

#pragma unroll
    for (int kk = 0; kk < 4; ++kk) {
      int rowa = kk * 32 + ra;
      int rowb = rowa + 4;
      bf16x8 ka0 = *(const bf16x8*)(Kc + rowa * 64 + posK0);
      bf16x8 ka1 = *(const bf16x8*)(Kc + rowa * 64 + posK1);
      bf16x8 kb0 = *(const bf16x8*)(Kc + rowb * 64 + posK0);
      bf16x8 kb1 = *(const bf16x8*)(Kc + rowb * 64 + posK1);
      bf16x8 vf[4];
#pragma unroll
      for (int ni = 0; ni < 4; ++ni) {
        int row = ni * 16 + l15;
        vf[ni] = *(const bf16x8*)(Vc + row * 128 + (((kk * 4 + g) ^ (row & 7)) * 8));
      }
#pragma unroll
      for (int mi = 0; mi < 2; ++mi) {
        f32x4 sa = (f32x4){0.f, 0.f, 0.f, 0.f};
        f32x4 sb = (f32x4){0.f, 0.f, 0.f, 0.f};
        sa = __builtin_amdgcn_mfma_f32_16x16x32_bf16(ka0, qf[mi][0], sa, 0, 0, 0);
        sa = __builtin_amdgcn_mfma_f32_16x16x32_bf16(ka1, qf[mi][1], sa, 0, 0, 0);
        sb = __builtin_amdgcn_mfma_f32_16x16x32_bf16(kb0, qf[mi][0], sb, 0, 0, 0);
        sb = __builtin_amdgcn_mfma_f32_16x16x32_bf16(kb1, qf[mi][1], sb, 0, 0, 0);
        float pa0 = __builtin_amdgcn_exp2f(sa[0]);
        float pa1 = __builtin_amdgcn_exp2f(sa[1]);
        float pa2 = __builtin_amdgcn_exp2f(sa[2]);
        float pa3 = __builtin_amdgcn_exp2f(sa[3]);
        float pb0 = __builtin_amdgcn_exp2f(sb[0]);
        float pb1 = __builtin_amdgcn_exp2f(sb[1]);
        float pb2 = __builtin_amdgcn_exp2f(sb[2]);
        float pb3 = __builtin_amdgcn_exp2f(sb[3]);
        union { bf16x8 v; unsigned int u[4]; } pf;
        pf.u[0] = __builtin_amdgcn_perm(__float_as_uint(pa1) + 0x8000u,
                                        __float_as_uint(pa0) + 0x8000u, 0x07060302u);
        pf.u[1] = __builtin_amdgcn_perm(__float_as_uint(pa3) + 0x8000u,
                                        __float_as_uint(pa2) + 0x8000u, 0x07060302u);
        pf.u[2] = __builtin_amdgcn_perm(__float_as_uint(pb1) + 0x8000u,
                                        __float_as_uint(pb0) + 0x8000u, 0x07060302u);
        pf.u[3] = __builtin_amdgcn_perm(__float_as_uint(pb3) + 0x8000u,
                                        __float_as_uint(pb2) + 0x8000u, 0x07060302u);
#pragma unroll
        for (int ni = 0; ni < 4; ++ni)
          of[mi][ni] = __builtin_amdgcn_mfma_f32_16x16x32_bf16(vf[ni], pf.v, of[mi][ni], 0, 0, 0);
        // row-sum on the matrix pipe: lacc[mi][*] = sum_k P[k][q=l15]
        lacc[mi] = __builtin_amdgcn_mfma_f32_16x16x32_bf16(onesf, pf.v, lacc[mi], 0, 0, 0);
      }
    }
  }

  // ---- epilogue: O^T / l, float4 stores (no shfl: lacc holds full sum) ----
#pragma unroll
  for (int mi = 0; mi < 2; ++mi) {
    float inv = 1.0f / lacc[mi][0];
    int qglob = qt * 256 + wave * 32 + mi * 16 + l15;
    float* obase = out + (size_t)(b * S_ + qglob) * H_ + h * HD_ + g * 4;
#pragma unroll
    for (int ni = 0; ni < 4; ++ni) {
      float4 vv;
      vv.x = of[mi][ni][0] * inv;
      vv.y = of[mi][ni][1] * inv;
      vv.z = of[mi][ni][2] * inv;
      vv.w = of[mi][ni][3] * inv;
      *(float4*)(obase + ni * 16) = vv;
    }
  }
}

extern "C" void kernel_launch(void* const* d_in, const int* in_sizes, int n_in,
                              void* d_out, int out_size, void* d_ws, size_t ws_size,
                              hipStream_t stream) {
  const float* hs = (const float*)d_in[0];
  const float* Wq = (const float*)d_in[1];
  const float* bq = (const float*)d_in[2];
  const float* Wk = (const float*)d_in[3];
  const float* bk = (const float*)d_in[4];
  const float* Wv = (const float*)d_in[5];
  const float* bv = (const float*)d_in[6];
  float* out = (float*)d_out;

  // ws (bf16): Xb[8M] | Wt[3M] | QKV[24M]; V slot holds Vt[bh][d][s].
  ushort_t* Xb  = (ushort_t*)d_ws;
  ushort_t* Wt  = Xb + 8388608u;
  ushort_t* QKV = Wt + 3145728u;
  ushort_t* Vtp = QKV + 16777216u;

  conv_x<<<8192, 256, 0, stream>>>((const float4*)hs, Xb);
  conv_w<<<768, 256, 0, stream>>>(Wq, Wk, Wv, Wt);
  qkv_gemm<<<dim3(24, 64), 256, 0, stream>>>(Xb, Wt, bq, bk, bv, QKV);
  attn<<<dim3(8, 64), 512, 0, stream>>>(QKV, Vtp, out);
}

// Round 10
// 227.937 us; speedup vs baseline: 1.0668x; 1.0239x over previous
//
#include <hip/hip_runtime.h>
#include <hip/hip_bf16.h>
#include <stdint.h>

#define B_ 4
#define S_ 2048
#define H_ 1024
#define NH_ 16
#define HD_ 64
#define SCALE_ 0.125f
#define LOG2E_ 1.4426950408889634f

typedef __bf16 bf16x8 __attribute__((ext_vector_type(8)));
typedef float f32x4 __attribute__((ext_vector_type(4)));
typedef unsigned short us4 __attribute__((ext_vector_type(4)));
typedef unsigned short us8 __attribute__((ext_vector_type(8)));
typedef unsigned short ushort_t;

__device__ __forceinline__ ushort_t f2bf(float f) {
  union { float f; uint32_t u; } a; a.f = f;
  uint32_t r = (a.u + 0x7fffu + ((a.u >> 16) & 1u)) >> 16;
  return (ushort_t)r;
}

__device__ __forceinline__ void async16(const void* g, void* l) {
  __builtin_amdgcn_global_load_lds(
      (const __attribute__((address_space(1))) unsigned int*)(uintptr_t)g,
      (__attribute__((address_space(3))) unsigned int*)(uintptr_t)l, 16, 0, 0);
}

// raw workgroup barrier: no implicit vmcnt/lgkmcnt drain (unlike
// __syncthreads, which drains the global_load_lds queue - m97's ~20% stall).
// "memory" clobber stops the compiler moving LDS/VMEM ops across it.
__device__ __forceinline__ void raw_barrier() {
  asm volatile("s_barrier" ::: "memory");
}

// ------- merged conversion kernel: one launch instead of two ---------
// blocks 0..8191: hidden_states fp32 -> bf16 (conv_x path)
// blocks 8192..8959: W conv+transpose W[k][n] -> Wt[w][n][k] (conv_w)
// Branch is block-uniform -> the barrier in the W path is safe.
__global__ __launch_bounds__(256) void conv_xw(const float4* __restrict__ x,
                                               ushort_t* __restrict__ xb,
                                               const float* __restrict__ Wq,
                                               const float* __restrict__ Wk,
                                               const float* __restrict__ Wv,
                                               ushort_t* __restrict__ Wt) {
  __shared__ __align__(16) ushort_t T[64 * 64];
  int bid = blockIdx.x;
  int tid = threadIdx.x;
  if (bid < 8192) {
    int i = bid * 256 + tid;
    float4 v = x[i];
    us4 o;
    o.x = f2bf(v.x); o.y = f2bf(v.y); o.z = f2bf(v.z); o.w = f2bf(v.w);
    *(us4*)(xb + (size_t)i * 4) = o;
    return;
  }
  int wid = bid - 8192;            // 0..767
  int w = wid >> 8;
  int t2 = wid & 255;
  int kt = (t2 >> 4) * 64, nt = (t2 & 15) * 64;
  const float* W = (w == 0) ? Wq : (w == 1) ? Wk : Wv;
  int k = tid >> 2, nq = tid & 3;
#pragma unroll
  for (int j4 = 0; j4 < 4; ++j4) {
    int n = nq * 4 + j4 * 16;
    float4 f = *(const float4*)(W + (size_t)(kt + k) * H_ + nt + n);
    us4 o;
    o.x = f2bf(f.x); o.y = f2bf(f.y); o.z = f2bf(f.z); o.w = f2bf(f.w);
    *(us4*)(T + k * 64 + (((n >> 3) ^ (k & 7)) * 8) + (n & 7)) = o;
  }
  __syncthreads();
  int n2 = tid >> 2, kq = tid & 3;
  us8 o0, o1;
#pragma unroll
  for (int j = 0; j < 16; ++j) {
    int kk = kq * 16 + j;
    ushort_t v = T[kk * 64 + (((n2 >> 3) ^ (kk & 7)) * 8) + (n2 & 7)];
    if (j < 8) o0[j] = v; else o1[j - 8] = v;
  }
  size_t obase = (size_t)w * (H_ * H_) + (size_t)(nt + n2) * H_ + kt + kq * 16;
  *(us8*)(Wt + obase) = o0;
  *(us8*)(Wt + obase + 8) = o1;
}

// ---------------- fused QKV GEMM (BK=64 + T3 single-barrier dbuf) ----
// Round-6 structure kept as-is: BK=64, XOR-8 swizzle, raw-barrier dbuf.
// w==2 (V) epilogue writes transposed [bh][d][s] into the V slot so attn
// can stage V^T directly.
__global__ __launch_bounds__(256) void qkv_gemm(const ushort_t* __restrict__ Xb,
                                                const ushort_t* __restrict__ Wt,
                                                const float* __restrict__ bq,
                                                const float* __restrict__ bk,
                                                const float* __restrict__ bv,
                                                ushort_t* __restrict__ QKV) {
  __shared__ __align__(16) ushort_t As0[128 * 64];   // 16 KB
  __shared__ __align__(16) ushort_t As1[128 * 64];   // 16 KB
  __shared__ __align__(16) ushort_t Bs0[128 * 64];   // 16 KB
  __shared__ __align__(16) ushort_t Bs1[128 * 64];   // 16 KB
  int nb = blockIdx.x;             // 0..23
  int mb = blockIdx.y;             // 0..63
  int w = nb >> 3;
  int n_base = (nb & 7) * 128;
  int m_base = mb * 128;
  const ushort_t* Wtw = Wt + (size_t)w * (H_ * H_);
  int tid = threadIdx.x;
  int lane = tid & 63, wave = tid >> 6;
  int wr = wave >> 1, wc = wave & 1;
  int g = lane >> 4, l15 = lane & 15;

  f32x4 acc[4][4];
#pragma unroll
  for (int i = 0; i < 4; i++)
#pragma unroll
    for (int j = 0; j < 4; j++) acc[i][j] = (f32x4){0.f, 0.f, 0.f, 0.f};

  // staging: 8 chunks/thread/iter (4 for A, 4 for B). chunk id = tid+it*256
  // -> (row = id>>3, slot = id&7); rows step by 32 per it (low 3 bits of
  // row invariant -> one source-column xor per thread).
  int r0 = tid >> 3, sl = tid & 7;
  int cc = sl ^ (r0 & 7);
  const ushort_t* sA = Xb + (size_t)(m_base + r0) * H_ + cc * 8;
  const ushort_t* sB = Wtw + (size_t)(n_base + r0) * H_ + cc * 8;
  int la = tid * 8;                // ushort offset of chunk id (it adds 2048)

  // prologue: stage tile 0, publish
#pragma unroll
  for (int it = 0; it < 4; ++it) {
    async16(sA + (size_t)it * 32 * H_, As0 + la + it * 2048);
    async16(sB + (size_t)it * 32 * H_, Bs0 + la + it * 2048);
  }
  __builtin_amdgcn_s_waitcnt(0xF70);   // vmcnt(0)
  raw_barrier();

  for (int kt = 0; kt < 16; ++kt) {
    const ushort_t* Ac = (kt & 1) ? As1 : As0;
    const ushort_t* Bc = (kt & 1) ? Bs1 : Bs0;
    ushort_t* An = (kt & 1) ? As0 : As1;
    ushort_t* Bn = (kt & 1) ? Bs0 : Bs1;
    if (kt < 15) {
      int k0 = (kt + 1) * 64;
#pragma unroll
      for (int it = 0; it < 4; ++it) {
        async16(sA + (size_t)it * 32 * H_ + k0, An + la + it * 2048);
        async16(sB + (size_t)it * 32 * H_ + k0, Bn + la + it * 2048);
      }
    }

#pragma unroll
    for (int ks = 0; ks < 2; ++ks) {
      bf16x8 af[4], bfr[4];
#pragma unroll
      for (int mi = 0; mi < 4; mi++) {
        int row = wr * 64 + mi * 16 + l15;
        af[mi] = *(const bf16x8*)(Ac + row * 64 + (((ks * 4 + g) ^ (row & 7)) * 8));
      }
#pragma unroll
      for (int ni = 0; ni < 4; ni++) {
        int row = wc * 64 + ni * 16 + l15;
        bfr[ni] = *(const bf16x8*)(Bc + row * 64 + (((ks * 4 + g) ^ (row & 7)) * 8));
      }
#pragma unroll
      for (int mi = 0; mi < 4; mi++)
#pragma unroll
        for (int ni = 0; ni < 4; ni++)
          acc[mi][ni] = __builtin_amdgcn_mfma_f32_16x16x32_bf16(af[mi], bfr[ni], acc[mi][ni], 0, 0, 0);
    }

    if (kt < 15) {
      __builtin_amdgcn_s_waitcnt(0xF70);   // vmcnt(0): tile kt+1 landed
      raw_barrier();                       // publish; no re-drain
    }
  }

  const float* bias = (w == 0) ? bq : (w == 1) ? bk : bv;
  float mult = (w == 0) ? SCALE_ * LOG2E_ : 1.0f;  // fold scale*log2e into Q
  if (w == 2) {
    // V: write transposed Vt[bh][d][s], 8B stores (4 consecutive s per lane)
    ushort_t* Vout = QKV + 16777216u;
#pragma unroll
    for (int ni = 0; ni < 4; ++ni) {
      int n_col = n_base + wc * 64 + ni * 16 + l15;
      float bb = bias[n_col];
      int hh = n_col >> 6, d = n_col & 63;
#pragma unroll
      for (int mi = 0; mi < 4; ++mi) {
        int m_row = m_base + wr * 64 + mi * 16 + g * 4;
        int bbi = m_row >> 11, s = m_row & 2047;
        us4 o;
#pragma unroll
        for (int reg = 0; reg < 4; ++reg) o[reg] = f2bf(acc[mi][ni][reg] + bb);
        *(us4*)(Vout + ((size_t)((bbi * 16 + hh) * 64 + d)) * 2048 + s) = o;
      }
    }
  } else {
    ushort_t* out = QKV + (size_t)w * (8192u * 1024u);
#pragma unroll
    for (int ni = 0; ni < 4; ++ni) {
      int n_col = n_base + wc * 64 + ni * 16 + l15;
      float bb = bias[n_col];
#pragma unroll
      for (int mi = 0; mi < 4; ++mi) {
        int m_row = m_base + wr * 64 + mi * 16 + g * 4;
#pragma unroll
        for (int reg = 0; reg < 4; ++reg) {
          float v = (acc[mi][ni][reg] + bb) * mult;
          out[(size_t)(m_row + reg) * H_ + n_col] = f2bf(v);
        }
      }
    }
  }
}

// ---------------- flash attention, zero-P-LDS form -------------------
// Round-10: exact revert to round-6's proven form (KVBLK=64, 8 waves x
// 32 q, raw barriers, counted vmcnt(2), conflicts=0, 79.0 us) — round
// 9's KVBLK=128 regressed (+7us, 4.19M bank conflicts). One addition:
// T5 s_setprio(1) wrapped tightly around the S-MFMA and PV-MFMA
// clusters (prio 0 through exp2/pack) — the catalog's attn-positive
// scheduling hint (m191: +4-7%).
// S^T via two interleaved-row MFMAs per 16-key group; P stays in regs.
// K staged with sigma_K(s)=((s>>3)&1)*4+(s&3); V with sigma_V(s)=s&7.
// Row-sum via ones-MFMA (lsum on the matrix pipe; no epilogue shfl).
__global__ __launch_bounds__(512, 4) void attn(const ushort_t* __restrict__ QKV,
                                               const ushort_t* __restrict__ Vt,
                                               float* __restrict__ out) {
  __shared__ __align__(16) ushort_t Ks[2][64 * 64];   // 16 KB
  __shared__ __align__(16) ushort_t Vs[2][64 * 64];   // 16 KB
  int qt = blockIdx.x;   // 0..7
  int bh = blockIdx.y;   // 0..63
  int b = bh >> 4, h = bh & 15;
  int tid = threadIdx.x, lane = tid & 63, wave = tid >> 6;  // wave 0..7
  int g = lane >> 4, l15 = lane & 15;

  const ushort_t* Qb = QKV;
  const ushort_t* Kb = QKV + 8388608u;

  // Q B-frags: 32 q rows per wave (scale*log2e pre-folded into Q)
  bf16x8 qf[2][2];
#pragma unroll
  for (int mi = 0; mi < 2; ++mi) {
    int q_row = qt * 256 + wave * 32 + mi * 16 + l15;
    size_t qoff = (size_t)(b * S_ + q_row) * H_ + h * HD_;
    qf[mi][0] = *(const bf16x8*)(Qb + qoff + g * 8);
    qf[mi][1] = *(const bf16x8*)(Qb + qoff + 32 + g * 8);
  }

  // all-ones A-fragment for the row-sum MFMA (bit pattern 0x3F80 = bf16 1.0)
  union { us8 u; bf16x8 v; } ones_u;
#pragma unroll
  for (int i = 0; i < 8; ++i) ones_u.u[i] = 0x3F80;
  bf16x8 onesf = ones_u.v;

  f32x4 of[2][4];
  f32x4 lacc[2];
#pragma unroll
  for (int mi = 0; mi < 2; mi++) {
    lacc[mi] = (f32x4){0.f, 0.f, 0.f, 0.f};
#pragma unroll
    for (int ni = 0; ni < 4; ni++) of[mi][ni] = (f32x4){0.f, 0.f, 0.f, 0.f};
  }

  // interleaved A-row for S^T: row_a = kk*32 + (l15>>2)*8 + (l15&3), row_b = +4
  int ra = (l15 >> 2) * 8 + (l15 & 3);
  int sKa = ((l15 >> 2) & 1) * 4 + (l15 & 3);   // sigma_K of both rows
  int posK0 = (g ^ sKa) * 8, posK1 = ((4 + g) ^ sKa) * 8;

  // staging: 512 threads x 1 chunk per 8KB tile (K and V each)
  int ch = tid;                    // 0..511
  int s0 = ch >> 3;
  int cK = (ch & 7) ^ ((((s0 >> 3) & 1) << 2) | (s0 & 3));
  int cV = (ch & 7) ^ (s0 & 7);
  const ushort_t* srcK = Kb + (size_t)(b * S_ + s0) * H_ + h * HD_ + cK * 8;
  const ushort_t* srcV = Vt + ((size_t)bh * 64 + s0) * S_ + cV * 8;

  // preload tile 0
  async16(srcK, Ks[0] + ch * 8);
  async16(srcV, Vs[0] + ch * 8);

  for (int kb = 0; kb < 32; ++kb) {
    int cur = kb & 1, nxt = cur ^ 1;
    raw_barrier();                      // all waves done reading buf[nxt]
    if (kb < 31) {
      async16(srcK + (size_t)(kb + 1) * 64 * H_, Ks[nxt] + ch * 8);
      async16(srcV + (size_t)(kb + 1) * 64, Vs[nxt] + ch * 8);
      __builtin_amdgcn_s_waitcnt(0xF72);   // vmcnt(2): tile kb landed
    } else {
      __builtin_amdgcn_s_waitcnt(0xF70);   // vmcnt(0)
    }
    raw_barrier();                      // publish tile kb (no re-drain)
    const ushort_t* Kc = Ks[cur];
    const ushort_t* Vc = Vs[cur];

#pragma unroll
    for (int kk = 0; kk < 2; ++kk) {
      int rowa = kk * 32 + ra;
      int rowb = rowa + 4;
      bf16x8 ka0 = *(const bf16x8*)(Kc + rowa * 64 + posK0);
      bf16x8 ka1 = *(const bf16x8*)(Kc + rowa * 64 + posK1);
      bf16x8 kb0 = *(const bf16x8*)(Kc + rowb * 64 + posK0);
      bf16x8 kb1 = *(const bf16x8*)(Kc + rowb * 64 + posK1);
      bf16x8 vf[4];
#pragma unroll
      for (int ni = 0; ni < 4; ++ni) {
        int row = ni * 16 + l15;
        vf[ni] = *(const bf16x8*)(Vc + row * 64 + (((kk * 4 + g) ^ (row & 7)) * 8));
      }
#pragma unroll
      for (int mi = 0; mi < 2; ++mi) {
        f32x4 sa = (f32x4){0.f, 0.f, 0.f, 0.f};
        f32x4 sb = (f32x4){0.f, 0.f, 0.f, 0.f};
        __builtin_amdgcn_s_setprio(1);
        sa = __builtin_amdgcn_mfma_f32_16x16x32_bf16(ka0, qf[mi][0], sa, 0, 0, 0);
        sa = __builtin_amdgcn_mfma_f32_16x16x32_bf16(ka1, qf[mi][1], sa, 0, 0, 0);
        sb = __builtin_amdgcn_mfma_f32_16x16x32_bf16(kb0, qf[mi][0], sb, 0, 0, 0);
        sb = __builtin_amdgcn_mfma_f32_16x16x32_bf16(kb1, qf[mi][1], sb, 0, 0, 0);
        __builtin_amdgcn_s_setprio(0);
        float pa0 = __builtin_amdgcn_exp2f(sa[0]);
        float pa1 = __builtin_amdgcn_exp2f(sa[1]);
        float pa2 = __builtin_amdgcn_exp2f(sa[2]);
        float pa3 = __builtin_amdgcn_exp2f(sa[3]);
        float pb0 = __builtin_amdgcn_exp2f(sb[0]);
        float pb1 = __builtin_amdgcn_exp2f(sb[1]);
        float pb2 = __builtin_amdgcn_exp2f(sb[2]);
        float pb3 = __builtin_amdgcn_exp2f(sb[3]);
        union { bf16x8 v; unsigned int u[4]; } pf;
        pf.u[0] = __builtin_amdgcn_perm(__float_as_uint(pa1) + 0x8000u,
                                        __float_as_uint(pa0) + 0x8000u, 0x07060302u);
        pf.u[1] = __builtin_amdgcn_perm(__float_as_uint(pa3) + 0x8000u,
                                        __float_as_uint(pa2) + 0x8000u, 0x07060302u);
        pf.u[2] = __builtin_amdgcn_perm(__float_as_uint(pb1) + 0x8000u,
                                        __float_as_uint(pb0) + 0x8000u, 0x07060302u);
        pf.u[3] = __builtin_amdgcn_perm(__float_as_uint(pb3) + 0x8000u,
                                        __float_as_uint(pb2) + 0x8000u, 0x07060302u);
        __builtin_amdgcn_s_setprio(1);
#pragma unroll
        for (int ni = 0; ni < 4; ++ni)
          of[mi][ni] = __builtin_amdgcn_mfma_f32_16x16x32_bf16(vf[ni], pf.v, of[mi][ni], 0, 0, 0);
        // row-sum on the matrix pipe: lacc[mi][*] = sum_k P[k][q=l15]
        lacc[mi] = __builtin_amdgcn_mfma_f32_16x16x32_bf16(onesf, pf.v, lacc[mi], 0, 0, 0);
        __builtin_amdgcn_s_setprio(0);
      }
    }
  }

  // ---- epilogue: O^T / l, float4 stores (no shfl: lacc holds full sum) ----
#pragma unroll
  for (int mi = 0; mi < 2; ++mi) {
    float inv = 1.0f / lacc[mi][0];
    int qglob = qt * 256 + wave * 32 + mi * 16 + l15;
    float* obase = out + (size_t)(b * S_ + qglob) * H_ + h * HD_ + g * 4;
#pragma unroll
    for (int ni = 0; ni < 4; ++ni) {
      float4 vv;
      vv.x = of[mi][ni][0] * inv;
      vv.y = of[mi][ni][1] * inv;
      vv.z = of[mi][ni][2] * inv;
      vv.w = of[mi][ni][3] * inv;
      *(float4*)(obase + ni * 16) = vv;
    }
  }
}

extern "C" void kernel_launch(void* const* d_in, const int* in_sizes, int n_in,
                              void* d_out, int out_size, void* d_ws, size_t ws_size,
                              hipStream_t stream) {
  const float* hs = (const float*)d_in[0];
  const float* Wq = (const float*)d_in[1];
  const float* bq = (const float*)d_in[2];
  const float* Wk = (const float*)d_in[3];
  const float* bk = (const float*)d_in[4];
  const float* Wv = (const float*)d_in[5];
  const float* bv = (const float*)d_in[6];
  float* out = (float*)d_out;

  // ws (bf16): Xb[8M] | Wt[3M] | QKV[24M]; V slot holds Vt[bh][d][s].
  ushort_t* Xb  = (ushort_t*)d_ws;
  ushort_t* Wt  = Xb + 8388608u;
  ushort_t* QKV = Wt + 3145728u;
  ushort_t* Vtp = QKV + 16777216u;

  conv_xw<<<8960, 256, 0, stream>>>((const float4*)hs, Xb, Wq, Wk, Wv, Wt);
  qkv_gemm<<<dim3(24, 64), 256, 0, stream>>>(Xb, Wt, bq, bk, bv, QKV);
  attn<<<dim3(8, 64), 512, 0, stream>>>(QKV, Vtp, out);
}